// Round 2
// baseline (310.955 us; speedup 1.0000x reference)
//
#include <hip/hip_runtime.h>
#include <cstdint>
#include <cstddef>

// ---------------------------------------------------------------------------
// HierarchicalQueryMatcher, N=2048, W=64, D=512.
//   LN1(x)@w1+b1 = rs*(A[n,:]+B[w,:]) - rs*mu*G + C
//   h2 = gelu(h) @ w2 (+b2 folded into qb) ; y = h2 + q[n] + b2
//   out = 16 * dot(LN2(y), cmhat)/max(||LN2(y)||,eps)
// Linear-in-h2 sums (S1,S3,S4,S6) are folded into extra GEMM columns:
//   W2X = [w2 | M6=w2@cmhg^T (64) | v1=w2@1, v3=w2@gg, v4=w2@gb | pad]  (608 cols)
// Quadratic sums (S2=sum y^2, S5=sum y^2*gg) streamed in the MFMA epilogue.
// ---------------------------------------------------------------------------

#define NQ 2048
#define NWC 64
#define DD 512
#define NCHUNK 19

typedef __attribute__((ext_vector_type(8))) short short8;
typedef __attribute__((ext_vector_type(8))) unsigned short ushort8;
typedef __attribute__((ext_vector_type(4))) float f32x4;

__device__ __forceinline__ unsigned short f2bf(float f) {
  unsigned u = __float_as_uint(f);
  u += 0x7fffu + ((u >> 16) & 1u);
  return (unsigned short)(u >> 16);
}

__device__ __forceinline__ unsigned cvtpk2(float lo, float hi) {
  unsigned r;
  asm("v_cvt_pk_bf16_f32 %0, %1, %2" : "=v"(r) : "v"(lo), "v"(hi));
  return r;
}

__device__ __forceinline__ float bf2f(unsigned short u) {
  return __uint_as_float(((unsigned)u) << 16);
}

// gelu(h) = h * sigmoid(z), z = h*(1.5957691 + 0.0713548*h^2); exp2-folded.
__device__ __forceinline__ float gelu_f(float h) {
  float h2 = h * h;
  float z2 = h * fmaf(h2, 0.10295890518f, 2.30221607f); // * log2(e)
  float e = exp2f(z2);
  return h * (e * __builtin_amdgcn_rcpf(e + 1.0f));
}

__device__ __forceinline__ float wred(float v) {
#pragma unroll
  for (int m = 1; m < 64; m <<= 1) v += __shfl_xor(v, m, 64);
  return v;
}

__device__ __forceinline__ float sel4(f32x4 v, int r) {
  float x = (r & 1) ? v[1] : v[0];
  float y = (r & 1) ? v[3] : v[2];
  return (r & 2) ? y : x;
}

// ---------------- small precompute kernels ----------------

__global__ void k_rowstats(const float* __restrict__ x, float* __restrict__ s,
                           float* __restrict__ ss) {
  int r = blockIdx.x;
  const float* row = x + (size_t)r * DD;
  float a = 0.f, b = 0.f;
  for (int c = threadIdx.x; c < DD; c += 256) {
    float v = row[c]; a += v; b = fmaf(v, v, b);
  }
  a = wred(a); b = wred(b);
  __shared__ float ra[4], rb[4];
  int wv = threadIdx.x >> 6;
  if ((threadIdx.x & 63) == 0) { ra[wv] = a; rb[wv] = b; }
  __syncthreads();
  if (threadIdx.x == 0) {
    s[r]  = ra[0] + ra[1] + ra[2] + ra[3];
    ss[r] = rb[0] + rb[1] + rb[2] + rb[3];
  }
}

// per class-memory row: cmhg = g2*cmhat, c1=sum g2*cmhat, c2=sum beta2*cmhat,
// c3 = sum b2*g2*cmhat
__global__ void k_cm(const float* __restrict__ cm, const float* __restrict__ g2,
                     const float* __restrict__ be2, const float* __restrict__ fc2b,
                     float* __restrict__ cmhg, float* __restrict__ c1,
                     float* __restrict__ c2, float* __restrict__ c3) {
  int w = blockIdx.x;
  const float* row = cm + (size_t)w * DD;
  float ss = 0.f;
  for (int c = threadIdx.x; c < DD; c += 256) { float v = row[c]; ss = fmaf(v, v, ss); }
  ss = wred(ss);
  __shared__ float rr[4]; __shared__ float s_inv;
  int wv = threadIdx.x >> 6;
  if ((threadIdx.x & 63) == 0) rr[wv] = ss;
  __syncthreads();
  if (threadIdx.x == 0) s_inv = 1.0f / fmaxf(sqrtf(rr[0]+rr[1]+rr[2]+rr[3]), 1e-12f);
  __syncthreads();
  float inv = s_inv;
  float a = 0.f, b = 0.f, d = 0.f;
  for (int c = threadIdx.x; c < DD; c += 256) {
    float ch = row[c] * inv;
    float gv = g2[c];
    float gch = gv * ch;
    cmhg[(size_t)w * DD + c] = gch;
    a += gch;
    b = fmaf(be2[c], ch, b);
    d = fmaf(fc2b[c], gch, d);
  }
  a = wred(a); b = wred(b); d = wred(d);
  __shared__ float rc1[4], rc2[4], rc3[4];
  if ((threadIdx.x & 63) == 0) { rc1[wv] = a; rc2[wv] = b; rc3[wv] = d; }
  __syncthreads();
  if (threadIdx.x == 0) {
    c1[w] = rc1[0]+rc1[1]+rc1[2]+rc1[3];
    c2[w] = rc2[0]+rc2[1]+rc2[2]+rc2[3];
    c3[w] = rc3[0]+rc3[1]+rc3[2]+rc3[3];
  }
}

__global__ void k_vec2(const float* __restrict__ g2, const float* __restrict__ b2v,
                       float* __restrict__ gg, float* __restrict__ gb,
                       float* __restrict__ scal) {
  int c = threadIdx.x; // 512
  float g = g2[c], b = b2v[c];
  gg[c] = g * g; gb[c] = g * b;
  float s0 = wred(g * g), s1 = wred(g * b), s2 = wred(b * b);
  __shared__ float r0[8], r1[8], r2[8];
  int wv = c >> 6;
  if ((c & 63) == 0) { r0[wv] = s0; r1[wv] = s1; r2[wv] = s2; }
  __syncthreads();
  if (c == 0) {
    float a=0,bb=0,cc=0;
    for (int i = 0; i < 8; ++i) { a+=r0[i]; bb+=r1[i]; cc+=r2[i]; }
    scal[0]=a; scal[1]=bb; scal[2]=cc;
  }
}

// per-n sums of qb = q+b2 with weights {1, gg, gb}
__global__ void k_qstats(const float* __restrict__ q, const float* __restrict__ b2,
                         const float* __restrict__ gg, const float* __restrict__ gb,
                         float* __restrict__ qst) {
  int n = blockIdx.x, ln = threadIdx.x; // 64 threads
  float s0 = 0.f, s1 = 0.f, s2 = 0.f;
#pragma unroll
  for (int j = 0; j < 8; ++j) {
    int c = ln + j * 64;
    float v = q[(size_t)n * DD + c] + b2[c];
    s0 += v; s1 = fmaf(v, gg[c], s1); s2 = fmaf(v, gb[c], s2);
  }
  s0 = wred(s0); s1 = wred(s1); s2 = wred(s2);
  if (ln == 0) { qst[n*4+0] = s0; qst[n*4+1] = s1; qst[n*4+2] = s2; }
}

__global__ void k_gc(const float* __restrict__ g1, const float* __restrict__ be1,
                     const float* __restrict__ w1, const float* __restrict__ b1,
                     float* __restrict__ G, float* __restrict__ C) {
  int j = blockIdx.x * 256 + threadIdx.x; // 512 total
  float g = 0.f, c = 0.f;
#pragma unroll 4
  for (int k = 0; k < 2 * DD; ++k) {
    float wv = w1[(size_t)k * DD + j];
    g = fmaf(g1[k], wv, g);
    c = fmaf(be1[k], wv, c);
  }
  G[j] = g;
  C[j] = c + b1[j];
}

// v1=w2@1, v3=w2@gg, v4=w2@gb -> Vbuf[k*4+{0,1,2}]
__global__ void k_vrows(const float* __restrict__ w2, const float* __restrict__ gg,
                        const float* __restrict__ gb, float* __restrict__ V) {
  int k = threadIdx.x; // 512, 1 block
  float s1 = 0.f, s3 = 0.f, s4 = 0.f;
  for (int d = 0; d < DD; d += 4) {
    f32x4 wv = *(const f32x4*)(w2 + (size_t)k * DD + d);
    f32x4 g4 = *(const f32x4*)(gg + d);
    f32x4 b4 = *(const f32x4*)(gb + d);
#pragma unroll
    for (int i = 0; i < 4; ++i) {
      s1 += wv[i];
      s3 = fmaf(wv[i], g4[i], s3);
      s4 = fmaf(wv[i], b4[i], s4);
    }
  }
  V[k*4+0] = s1; V[k*4+1] = s3; V[k*4+2] = s4; V[k*4+3] = 0.f;
}

// pack W[512 rows from roff][512 cols] into MFMA fragment order (opt. row scale)
__global__ void k_pack(const float* __restrict__ W, const float* __restrict__ scale,
                       int roff, unsigned short* __restrict__ out) {
  int tid = blockIdx.x * 512 + threadIdx.x; // 32768
  int l = tid & 63;
  int t = (tid >> 6) & 15;
  int ct = tid >> 10;
  int g = l >> 4;
  int col = (ct << 4) + (l & 15);
  ushort8 o;
#pragma unroll
  for (int i = 0; i < 8; ++i) {
    int k = t * 32 + g * 8 + i;
    float v = W[(size_t)(roff + k) * DD + col];
    if (scale) v *= scale[roff + k];
    o[i] = f2bf(v);
  }
  *(ushort8*)(out + (size_t)tid * 8) = o;
}

// pack cmhg^T: operand[k=d][col=w] = cmhg[w][d], 64 cols (4 ct)
__global__ void k_packT(const float* __restrict__ cmhg, unsigned short* __restrict__ out) {
  int tid = blockIdx.x * 512 + threadIdx.x; // 4096
  int l = tid & 63;
  int t = (tid >> 6) & 15;
  int g = l >> 4;
  int col = ((tid >> 10) << 4) + (l & 15);
  ushort8 o;
#pragma unroll
  for (int i = 0; i < 8; ++i) {
    int k = t * 32 + g * 8 + i;
    o[i] = f2bf(cmhg[(size_t)col * DD + k]);
  }
  *(ushort8*)(out + (size_t)tid * 8) = o;
}

// pack composed W2X = [w2 | M6 | v1 v3 v4 | pad], 608 cols (38 ct)
__global__ void k_packX(const float* __restrict__ w2, const float* __restrict__ M6,
                        const float* __restrict__ V, unsigned short* __restrict__ out) {
  int tid = blockIdx.x * 512 + threadIdx.x; // 38912
  int l = tid & 63;
  int t = (tid >> 6) & 15;
  int ct = tid >> 10;
  int g = l >> 4;
  int col = (ct << 4) + (l & 15);
  ushort8 o;
#pragma unroll
  for (int i = 0; i < 8; ++i) {
    int k = t * 32 + g * 8 + i;
    float v;
    if (col < 512)       v = w2[(size_t)k * DD + col];
    else if (col < 576)  v = M6[(size_t)k * 64 + (col - 512)];
    else { int cv = col - 576; v = (cv < 3) ? V[k*4+cv] : 0.f; }
    o[i] = f2bf(v);
  }
  *(ushort8*)(out + (size_t)tid * 8) = o;
}

// OUT[M,ncols] = bf16(X[M,512]) @ packedW ; grid=(ncoltiles/4, M/64), 256 thr
__global__ __launch_bounds__(256) void k_gemm16(const float* __restrict__ X,
    const unsigned short* __restrict__ PW, void* __restrict__ Out,
    int ostride, int obf) {
  int l = threadIdx.x & 63;
  int wv = threadIdx.x >> 6;
  int lr = l & 15, g = l >> 4;
  int r0 = blockIdx.y * 64 + wv * 16;
  int cb0 = blockIdx.x * 4;
  f32x4 acc[4] = {{0,0,0,0},{0,0,0,0},{0,0,0,0},{0,0,0,0}};
  const float* xrow = X + (size_t)(r0 + lr) * DD;
#pragma unroll
  for (int t = 0; t < 16; ++t) {
    int kb = t * 32 + g * 8;
    f32x4 x0 = *(const f32x4*)(xrow + kb);
    f32x4 x1 = *(const f32x4*)(xrow + kb + 4);
    union { short8 s; unsigned u[4]; } af;
    af.u[0] = cvtpk2(x0[0], x0[1]);
    af.u[1] = cvtpk2(x0[2], x0[3]);
    af.u[2] = cvtpk2(x1[0], x1[1]);
    af.u[3] = cvtpk2(x1[2], x1[3]);
#pragma unroll
    for (int c = 0; c < 4; ++c) {
      short8 bf = *(const short8*)(PW + (size_t)(((cb0 + c) * 16 + t) * 64 + l) * 8);
      acc[c] = __builtin_amdgcn_mfma_f32_16x16x32_bf16(af.s, bf, acc[c], 0, 0, 0);
    }
  }
#pragma unroll
  for (int c = 0; c < 4; ++c)
#pragma unroll
    for (int r = 0; r < 4; ++r) {
      size_t idx = (size_t)(r0 + g * 4 + r) * ostride + (cb0 + c) * 16 + lr;
      float v = acc[c][r];
      if (obf) ((unsigned short*)Out)[idx] = f2bf(v);
      else     ((float*)Out)[idx] = v;
    }
}

// ---------------- fused main kernel ----------------

__device__ __forceinline__ void async16(const void* g, void* lds) {
  __builtin_amdgcn_global_load_lds(
      (const __attribute__((address_space(1))) void*)(uintptr_t)g,
      (__attribute__((address_space(3))) void*)(unsigned int)(uintptr_t)lds,
      16, 0, 0);
}

__global__ __launch_bounds__(512, 2) void k_main(
    const float* __restrict__ Afull, const unsigned short* __restrict__ Bwb,
    const float* __restrict__ G, const float* __restrict__ Cc,
    const float* __restrict__ q, const float* __restrict__ b2,
    const float* __restrict__ gg, const float* __restrict__ qst,
    const float* __restrict__ QC, const float* __restrict__ c1v,
    const float* __restrict__ c2v, const float* __restrict__ c3v,
    const float* __restrict__ Sq, const float* __restrict__ SSq,
    const float* __restrict__ Sc, const float* __restrict__ SSc,
    const float* __restrict__ scal, const unsigned short* __restrict__ PW2X,
    float* __restrict__ out) {

  __shared__ __align__(16) float sG[DD], sC[DD], sGG[DD];
  __shared__ __align__(16) float sA[4][DD], sQB[4][DD];
  __shared__ __align__(16) unsigned short sBw[64 * DD];   // bf16, XOR-swizzled rows
  __shared__ __align__(16) unsigned short sW[2][16384];   // w2x chunk dbuf (32KB each)

  const int tid = threadIdx.x;
  const int wv = tid >> 6, l = tid & 63;
  const int g = l >> 4, lr = l & 15;
  const int n0 = blockIdx.x * 4;
  const int sub = wv >> 1;
  const int n = n0 + sub;
  const int whalf = wv & 1;
  const int w0 = whalf * 32 + lr;
  const int w1p = w0 + 16;

  // ---- stage block-wide LDS state ----
  sG[tid] = G[tid]; sC[tid] = Cc[tid]; sGG[tid] = gg[tid];
#pragma unroll
  for (int s = 0; s < 4; ++s) {
    sA[s][tid]  = Afull[(size_t)(n0 + s) * DD + tid];
    sQB[s][tid] = q[(size_t)(n0 + s) * DD + tid] + b2[tid];
  }
  // Bw bf16 -> LDS with XOR swizzle (row stride 1024B; byte ^= (row&7)<<4)
#pragma unroll
  for (int j = 0; j < 8; ++j) {
    int idx = j * 512 + tid;            // 16B-chunk id (4096 total)
    int row = idx >> 6, c16 = idx & 63;
    ushort8 v = *(const ushort8*)(Bwb + (size_t)idx * 8);
    int byteoff = (c16 * 16) ^ ((row & 7) << 4);
    *(ushort8*)((char*)sBw + row * 1024 + byteoff) = v;
  }
  // issue w2x chunk 0 prefetch (overlaps gelu generation)
#pragma unroll
  for (int j = 0; j < 4; ++j)
    async16(PW2X + (size_t)(j * 512 + tid) * 8, &sW[0][(j * 512 + wv * 64) * 8]);

  __syncthreads();

  // ---- LN1 scalars for this lane's two (n,w) pairs ----
  float sqn = Sq[n], ssqn = SSq[n];
  float mu0 = (sqn + Sc[w0]) * (1.0f / 1024.0f);
  float rs0 = rsqrtf((ssqn + SSc[w0]) * (1.0f / 1024.0f) - mu0 * mu0 + 1e-5f);
  float mu1 = (sqn + Sc[w1p]) * (1.0f / 1024.0f);
  float rs1 = rsqrtf((ssqn + SSc[w1p]) * (1.0f / 1024.0f) - mu1 * mu1 + 1e-5f);
  float al0 = rs0, bl0 = -rs0 * mu0;
  float al1 = rs1, bl1 = -rs1 * mu1;

  // ---- gelu fragments straight into MFMA B-operand layout ----
  short8 af0[16], af1[16];
  const int swz0 = (w0 & 7) << 4, swz1 = (w1p & 7) << 4;
#pragma unroll
  for (int t = 0; t < 16; ++t) {
    int kb = t * 32 + g * 8;
    f32x4 a0 = *(const f32x4*)&sA[sub][kb];
    f32x4 a1 = *(const f32x4*)&sA[sub][kb + 4];
    f32x4 g0 = *(const f32x4*)&sG[kb];
    f32x4 g1v = *(const f32x4*)&sG[kb + 4];
    f32x4 c0 = *(const f32x4*)&sC[kb];
    f32x4 c1f = *(const f32x4*)&sC[kb + 4];
    int bo = t * 64 + g * 16;
    ushort8 ub0 = *(const ushort8*)((const char*)sBw + w0 * 1024 + (bo ^ swz0));
    ushort8 ub1 = *(const ushort8*)((const char*)sBw + w1p * 1024 + (bo ^ swz1));
    float hA[8], hB[8];
#pragma unroll
    for (int i = 0; i < 4; ++i) {
      float in0 = fmaf(bl0, g0[i], c0[i]);
      float in1 = fmaf(bl1, g0[i], c0[i]);
      hA[i] = gelu_f(fmaf(al0, a0[i] + bf2f(ub0[i]), in0));
      hB[i] = gelu_f(fmaf(al1, a0[i] + bf2f(ub1[i]), in1));
      float jn0 = fmaf(bl0, g1v[i], c1f[i]);
      float jn1 = fmaf(bl1, g1v[i], c1f[i]);
      hA[4+i] = gelu_f(fmaf(al0, a1[i] + bf2f(ub0[4+i]), jn0));
      hB[4+i] = gelu_f(fmaf(al1, a1[i] + bf2f(ub1[4+i]), jn1));
    }
    union { short8 s; unsigned u[4]; } pa, pb;
    pa.u[0] = cvtpk2(hA[0], hA[1]); pa.u[1] = cvtpk2(hA[2], hA[3]);
    pa.u[2] = cvtpk2(hA[4], hA[5]); pa.u[3] = cvtpk2(hA[6], hA[7]);
    pb.u[0] = cvtpk2(hB[0], hB[1]); pb.u[1] = cvtpk2(hB[2], hB[3]);
    pb.u[2] = cvtpk2(hB[4], hB[5]); pb.u[3] = cvtpk2(hB[6], hB[7]);
    af0[t] = pa.s; af1[t] = pb.s;
  }

  float S20 = 0.f, S50 = 0.f, S21 = 0.f, S51 = 0.f;
  float m6d0 = 0.f, m6d1 = 0.f;
  float v1d0 = 0.f, v3d0 = 0.f, v4d0 = 0.f;
  float v1d1 = 0.f, v3d1 = 0.f, v4d1 = 0.f;

  for (int cc = 0; cc < NCHUNK; ++cc) {
    __syncthreads();                    // chunk cc staged; prev chunk reads done
    if (cc < NCHUNK - 1) {              // prefetch next chunk
      const unsigned short* src = PW2X + (size_t)(cc + 1) * 16384;
      unsigned short* dst = sW[(cc + 1) & 1];
#pragma unroll
      for (int j = 0; j < 4; ++j)
        async16(src + (size_t)(j * 512 + tid) * 8, &dst[(j * 512 + wv * 64) * 8]);
    }
    const unsigned short* wbuf = sW[cc & 1];

    if (cc < 16) {
      f32x4 acc00 = {0,0,0,0}, acc01 = {0,0,0,0}, acc10 = {0,0,0,0}, acc11 = {0,0,0,0};
#pragma unroll
      for (int t = 0; t < 16; ++t) {
        short8 bf0 = *(const short8*)(wbuf + (size_t)((t * 64 + l) * 8));
        short8 bf1 = *(const short8*)(wbuf + (size_t)(((16 + t) * 64 + l) * 8));
        acc00 = __builtin_amdgcn_mfma_f32_16x16x32_bf16(bf0, af0[t], acc00, 0, 0, 0);
        acc10 = __builtin_amdgcn_mfma_f32_16x16x32_bf16(bf0, af1[t], acc10, 0, 0, 0);
        acc01 = __builtin_amdgcn_mfma_f32_16x16x32_bf16(bf1, af0[t], acc01, 0, 0, 0);
        acc11 = __builtin_amdgcn_mfma_f32_16x16x32_bf16(bf1, af1[t], acc11, 0, 0, 0);
      }
#pragma unroll
      for (int ct = 0; ct < 2; ++ct) {
        int cb = cc * 32 + ct * 16 + g * 4;
        f32x4 qb4 = *(const f32x4*)&sQB[sub][cb];
        f32x4 gg4 = *(const f32x4*)&sGG[cb];
        f32x4 aAv = ct ? acc01 : acc00;
        f32x4 aBv = ct ? acc11 : acc10;
#pragma unroll
        for (int r = 0; r < 4; ++r) {
          float y = aAv[r] + qb4[r];
          float y2 = y * y;
          S20 += y2; S50 = fmaf(y2, gg4[r], S50);
          float z = aBv[r] + qb4[r];
          float z2 = z * z;
          S21 += z2; S51 = fmaf(z2, gg4[r], S51);
        }
      }
    } else if (cc == 16 + whalf) {
      // M6 chunk containing this wave's rows: extract diagonal dots
      f32x4 acc00 = {0,0,0,0}, acc11 = {0,0,0,0};
#pragma unroll
      for (int t = 0; t < 16; ++t) {
        short8 bf0 = *(const short8*)(wbuf + (size_t)((t * 64 + l) * 8));
        short8 bf1 = *(const short8*)(wbuf + (size_t)(((16 + t) * 64 + l) * 8));
        acc00 = __builtin_amdgcn_mfma_f32_16x16x32_bf16(bf0, af0[t], acc00, 0, 0, 0);
        acc11 = __builtin_amdgcn_mfma_f32_16x16x32_bf16(bf1, af1[t], acc11, 0, 0, 0);
      }
      float d0 = sel4(acc00, lr & 3);
      float d1 = sel4(acc11, lr & 3);
      int src = lr + ((lr >> 2) << 4);
      m6d0 = __shfl(d0, src, 64);
      m6d1 = __shfl(d1, src, 64);
    } else if (cc == 18) {
      // v-chunk: v1,v3,v4 at within-tile cols 0,1,2 (ct0 only)
      f32x4 acc00 = {0,0,0,0}, acc10 = {0,0,0,0};
#pragma unroll
      for (int t = 0; t < 16; ++t) {
        short8 bf0 = *(const short8*)(wbuf + (size_t)((t * 64 + l) * 8));
        acc00 = __builtin_amdgcn_mfma_f32_16x16x32_bf16(bf0, af0[t], acc00, 0, 0, 0);
        acc10 = __builtin_amdgcn_mfma_f32_16x16x32_bf16(bf0, af1[t], acc10, 0, 0, 0);
      }
      v1d0 = __shfl(acc00[0], lr, 64);
      v3d0 = __shfl(acc00[1], lr, 64);
      v4d0 = __shfl(acc00[2], lr, 64);
      v1d1 = __shfl(acc10[0], lr, 64);
      v3d1 = __shfl(acc10[1], lr, 64);
      v4d1 = __shfl(acc10[2], lr, 64);
    }
    // (wave skips the other M6 chunk entirely)
  }

  // reduce quadratic sums over the 4 g-groups
  S20 += __shfl_xor(S20, 16, 64); S20 += __shfl_xor(S20, 32, 64);
  S50 += __shfl_xor(S50, 16, 64); S50 += __shfl_xor(S50, 32, 64);
  S21 += __shfl_xor(S21, 16, 64); S21 += __shfl_xor(S21, 32, 64);
  S51 += __shfl_xor(S51, 16, 64); S51 += __shfl_xor(S51, 32, 64);

  if (g == 0) {
    float sg2v = scal[0], sgbv = scal[1], sb2v = scal[2];
    float qbs = qst[n*4+0], qggs = qst[n*4+1], qgbs = qst[n*4+2];
#pragma unroll
    for (int p = 0; p < 2; ++p) {
      int w = whalf * 32 + p * 16 + lr;
      float S1 = (p ? v1d1 : v1d0) + qbs;
      float S2 = (p ? S21 : S20);
      float S3 = (p ? v3d1 : v3d0) + qggs;
      float S4 = (p ? v4d1 : v4d0) + qgbs;
      float S5 = (p ? S51 : S50);
      float S6 = (p ? m6d1 : m6d0) + QC[(size_t)n * NWC + w] + c3v[w];
      float mu2 = S1 * (1.0f / 512.0f);
      float var2 = S2 * (1.0f / 512.0f) - mu2 * mu2;
      float rs2 = rsqrtf(var2 + 1e-5f);
      float n2 = rs2 * rs2 * (S5 - 2.f * mu2 * S3 + mu2 * mu2 * sg2v)
               + 2.f * rs2 * (S4 - mu2 * sgbv) + sb2v;
      float num = rs2 * (S6 - mu2 * c1v[w]) + c2v[w];
      out[(size_t)n * NWC + w] = 16.0f * num / fmaxf(sqrtf(fmaxf(n2, 0.f)), 1e-12f);
    }
  }
}

// ---------------- launch ----------------

extern "C" void kernel_launch(void* const* d_in, const int* in_sizes, int n_in,
                              void* d_out, int out_size, void* d_ws, size_t ws_size,
                              hipStream_t stream) {
  const float* q    = (const float*)d_in[0];
  const float* cm   = (const float*)d_in[1];
  const float* ln1w = (const float*)d_in[2];
  const float* ln1b = (const float*)d_in[3];
  const float* w1   = (const float*)d_in[4];
  const float* b1   = (const float*)d_in[5];
  const float* w2   = (const float*)d_in[6];
  const float* b2   = (const float*)d_in[7];
  const float* ln2w = (const float*)d_in[8];
  const float* ln2b = (const float*)d_in[9];
  float* out = (float*)d_out;

  char* p = (char*)d_ws;
  auto alloc = [&](size_t bytes) { char* r = p; p += (bytes + 255) & ~(size_t)255; return r; };
  float* A     = (float*)alloc((size_t)NQ * DD * 4);
  unsigned short* Bwb = (unsigned short*)alloc((size_t)NWC * DD * 2);
  float* G     = (float*)alloc(DD * 4);
  float* C     = (float*)alloc(DD * 4);
  float* Sq    = (float*)alloc(NQ * 4);
  float* SSq   = (float*)alloc(NQ * 4);
  float* Sc    = (float*)alloc(NWC * 4);
  float* SSc   = (float*)alloc(NWC * 4);
  float* cmhg  = (float*)alloc((size_t)NWC * DD * 4);
  float* c1    = (float*)alloc(NWC * 4);
  float* c2    = (float*)alloc(NWC * 4);
  float* c3    = (float*)alloc(NWC * 4);
  float* gg    = (float*)alloc(DD * 4);
  float* gb    = (float*)alloc(DD * 4);
  float* scal  = (float*)alloc(256);
  float* qst   = (float*)alloc((size_t)NQ * 4 * 4);
  float* QC    = (float*)alloc((size_t)NQ * NWC * 4);
  float* M6buf = (float*)alloc((size_t)DD * NWC * 4);
  float* Vbuf  = (float*)alloc((size_t)DD * 4 * 4);
  unsigned short* PW1T = (unsigned short*)alloc((size_t)DD * DD * 2);
  unsigned short* PW1B = (unsigned short*)alloc((size_t)DD * DD * 2);
  unsigned short* PCT  = (unsigned short*)alloc((size_t)DD * NWC * 2);
  unsigned short* PW2X = (unsigned short*)alloc((size_t)NCHUNK * 16384 * 2);

  k_rowstats<<<NQ, 256, 0, stream>>>(q, Sq, SSq);
  k_rowstats<<<NWC, 256, 0, stream>>>(cm, Sc, SSc);
  k_vec2<<<1, 512, 0, stream>>>(ln2w, ln2b, gg, gb, scal);
  k_cm<<<NWC, 256, 0, stream>>>(cm, ln2w, ln2b, b2, cmhg, c1, c2, c3);
  k_qstats<<<NQ, 64, 0, stream>>>(q, b2, gg, gb, qst);
  k_gc<<<2, 256, 0, stream>>>(ln1w, ln1b, w1, b1, G, C);
  k_vrows<<<1, 512, 0, stream>>>(w2, gg, gb, Vbuf);
  k_pack<<<64, 512, 0, stream>>>(w1, ln1w, 0, PW1T);
  k_pack<<<64, 512, 0, stream>>>(w1, ln1w, 512, PW1B);
  k_packT<<<8, 512, 0, stream>>>(cmhg, PCT);
  k_gemm16<<<dim3(8, 32), 256, 0, stream>>>(q, PW1T, A, DD, 0);
  k_gemm16<<<dim3(8, 1), 256, 0, stream>>>(cm, PW1B, Bwb, DD, 1);
  k_gemm16<<<dim3(1, 32), 256, 0, stream>>>(q, PCT, QC, NWC, 0);
  k_gemm16<<<dim3(1, 8), 256, 0, stream>>>(w2, PCT, M6buf, NWC, 0);
  k_packX<<<76, 512, 0, stream>>>(w2, M6buf, Vbuf, PW2X);
  k_main<<<512, 512, 0, stream>>>(A, Bwb, G, C, q, b2, gg, qst, QC, c1, c2, c3,
                                  Sq, SSq, Sc, SSc, scal, PW2X, out);
}

// Round 3
// 135.332 us; speedup vs baseline: 2.2977x; 2.2977x over previous
//
#include <hip/hip_runtime.h>
#include <cstdint>
#include <cstddef>

// ---------------------------------------------------------------------------
// HierarchicalQueryMatcher, N=2048, W=64, D=512.
//   LN1(x)@w1+b1 = rs*(A[n,:]+B[w,:]) - rs*mu*G + C
//   h2 = gelu(h) @ w2 ; y = h2 + q[n] + b2
//   out = 16 * dot(LN2(y), cmhat)/max(||LN2(y)||,eps)
// Linear-in-h2 sums folded into extra GEMM cols (M6 = w2@cmhg^T, v1,v3,v4);
// quadratic sums (S2, S5) streamed in the MFMA epilogue.
// 5 launches: k_prep -> k_pack1 -> k_gemms -> k_pack2 -> k_main.
// ---------------------------------------------------------------------------

#define NQ 2048
#define NWC 64
#define DD 512
#define NCHUNK 19

typedef __attribute__((ext_vector_type(8))) short short8;
typedef __attribute__((ext_vector_type(8))) unsigned short ushort8;
typedef __attribute__((ext_vector_type(4))) float f32x4;

__device__ __forceinline__ unsigned short f2bf(float f) {
  unsigned u = __float_as_uint(f);
  u += 0x7fffu + ((u >> 16) & 1u);
  return (unsigned short)(u >> 16);
}

__device__ __forceinline__ unsigned cvtpk2(float lo, float hi) {
  unsigned r;
  asm("v_cvt_pk_bf16_f32 %0, %1, %2" : "=v"(r) : "v"(lo), "v"(hi));
  return r;
}

__device__ __forceinline__ float bf2f(unsigned short u) {
  return __uint_as_float(((unsigned)u) << 16);
}

__device__ __forceinline__ float gelu_f(float h) {
  float h2 = h * h;
  float z2 = h * fmaf(h2, 0.10295890518f, 2.30221607f); // *log2(e)
  float e = exp2f(z2);
  return h * (e * __builtin_amdgcn_rcpf(e + 1.0f));
}

__device__ __forceinline__ float wred(float v) {
#pragma unroll
  for (int m = 1; m < 64; m <<= 1) v += __shfl_xor(v, m, 64);
  return v;
}

__device__ __forceinline__ float sel4(f32x4 v, int r) {
  float x = (r & 1) ? v[1] : v[0];
  float y = (r & 1) ? v[3] : v[2];
  return (r & 2) ? y : x;
}

// ---------------- k_prep: all O(N*D) precompute in one launch ----------------
// blocks 0..255   : q row stats (8 rows/block): Sq, SSq, qst[3]
// blocks 256..319 : cm rows: Sc, SSc, cmhg, c1, c2, c3
// blocks 320..335 : G/C partials over 64 k-rows each -> Gp, Cp
// blocks 336..399 : vrows (w2 row dots with 1, gg, gb) -> V
// block  400      : gg array + scal[3]
__global__ __launch_bounds__(256) void k_prep(
    const float* __restrict__ q, const float* __restrict__ cm,
    const float* __restrict__ g1, const float* __restrict__ be1,
    const float* __restrict__ w1, const float* __restrict__ w2,
    const float* __restrict__ g2, const float* __restrict__ be2,
    const float* __restrict__ b2,
    float* __restrict__ Sq, float* __restrict__ SSq, float* __restrict__ qst,
    float* __restrict__ Sc, float* __restrict__ SSc, float* __restrict__ cmhg,
    float* __restrict__ c1, float* __restrict__ c2, float* __restrict__ c3,
    float* __restrict__ Gp, float* __restrict__ Cp, float* __restrict__ V,
    float* __restrict__ gg, float* __restrict__ scal) {
  const int b = blockIdx.x, tid = threadIdx.x;
  const int wv = tid >> 6, l = tid & 63;
  __shared__ float shr[3][4];
  __shared__ float s_inv;

  if (b < 256) {
    // ---- q stats: 8 rows, wave handles 2 rows, lane covers cols [l*8,l*8+8)
    f32x4 b20 = *(const f32x4*)(b2 + l * 8);
    f32x4 b21 = *(const f32x4*)(b2 + l * 8 + 4);
    f32x4 g20 = *(const f32x4*)(g2 + l * 8);
    f32x4 g21 = *(const f32x4*)(g2 + l * 8 + 4);
    f32x4 e20 = *(const f32x4*)(be2 + l * 8);
    f32x4 e21 = *(const f32x4*)(be2 + l * 8 + 4);
#pragma unroll
    for (int rr = 0; rr < 2; ++rr) {
      int r = b * 8 + wv * 2 + rr;
      const float* row = q + (size_t)r * DD;
      f32x4 q0 = *(const f32x4*)(row + l * 8);
      f32x4 q1 = *(const f32x4*)(row + l * 8 + 4);
      float s0 = 0, s1 = 0, s2 = 0, s3 = 0, s4 = 0;
#pragma unroll
      for (int i = 0; i < 4; ++i) {
        float v = q0[i]; s0 += v; s1 = fmaf(v, v, s1);
        float qb = v + b20[i], g = g20[i];
        s2 += qb; s3 = fmaf(qb, g * g, s3); s4 = fmaf(qb, g * e20[i], s4);
        v = q1[i]; s0 += v; s1 = fmaf(v, v, s1);
        qb = v + b21[i]; g = g21[i];
        s2 += qb; s3 = fmaf(qb, g * g, s3); s4 = fmaf(qb, g * e21[i], s4);
      }
      s0 = wred(s0); s1 = wred(s1); s2 = wred(s2); s3 = wred(s3); s4 = wred(s4);
      if (l == 0) {
        Sq[r] = s0; SSq[r] = s1;
        qst[r * 4 + 0] = s2; qst[r * 4 + 1] = s3; qst[r * 4 + 2] = s4;
      }
    }
  } else if (b < 320) {
    // ---- cm row w
    int w = b - 256;
    const float* row = cm + (size_t)w * DD;
    float sm = 0.f, ss = 0.f;
    for (int c = tid; c < DD; c += 256) { float v = row[c]; sm += v; ss = fmaf(v, v, ss); }
    sm = wred(sm); ss = wred(ss);
    if (l == 0) { shr[0][wv] = sm; shr[1][wv] = ss; }
    __syncthreads();
    if (tid == 0) {
      float smt = shr[0][0] + shr[0][1] + shr[0][2] + shr[0][3];
      float sst = shr[1][0] + shr[1][1] + shr[1][2] + shr[1][3];
      Sc[w] = smt; SSc[w] = sst;
      s_inv = 1.0f / fmaxf(sqrtf(sst), 1e-12f);
    }
    __syncthreads();
    float inv = s_inv;
    float a = 0.f, bs = 0.f, d = 0.f;
    for (int c = tid; c < DD; c += 256) {
      float ch = row[c] * inv;
      float gv = g2[c];
      float gch = gv * ch;
      cmhg[(size_t)w * DD + c] = gch;
      a += gch;
      bs = fmaf(be2[c], ch, bs);
      d = fmaf(b2[c], gch, d);
    }
    a = wred(a); bs = wred(bs); d = wred(d);
    __syncthreads();
    if (l == 0) { shr[0][wv] = a; shr[1][wv] = bs; shr[2][wv] = d; }
    __syncthreads();
    if (tid == 0) {
      c1[w] = shr[0][0] + shr[0][1] + shr[0][2] + shr[0][3];
      c2[w] = shr[1][0] + shr[1][1] + shr[1][2] + shr[1][3];
      c3[w] = shr[2][0] + shr[2][1] + shr[2][2] + shr[2][3];
    }
  } else if (b < 336) {
    // ---- G/C partials: k-rows [bk*64, bk*64+64)
    int bk = b - 320, k0 = bk * 64;
#pragma unroll
    for (int jh = 0; jh < 2; ++jh) {
      int j = tid + jh * 256;
      float g = 0.f, c = 0.f;
#pragma unroll 4
      for (int k = 0; k < 64; ++k) {
        float wv4 = w1[(size_t)(k0 + k) * DD + j];
        g = fmaf(g1[k0 + k], wv4, g);
        c = fmaf(be1[k0 + k], wv4, c);
      }
      Gp[(size_t)bk * DD + j] = g;
      Cp[(size_t)bk * DD + j] = c;
    }
  } else if (b < 400) {
    // ---- vrows: w2 rows [bb*8, bb*8+8), wave handles 2 rows
    int bb = b - 336;
    f32x4 g20 = *(const f32x4*)(g2 + l * 8);
    f32x4 g21 = *(const f32x4*)(g2 + l * 8 + 4);
    f32x4 e20 = *(const f32x4*)(be2 + l * 8);
    f32x4 e21 = *(const f32x4*)(be2 + l * 8 + 4);
#pragma unroll
    for (int rr = 0; rr < 2; ++rr) {
      int k = bb * 8 + wv * 2 + rr;
      const float* row = w2 + (size_t)k * DD;
      f32x4 w0 = *(const f32x4*)(row + l * 8);
      f32x4 w1v = *(const f32x4*)(row + l * 8 + 4);
      float s1 = 0, s3 = 0, s4 = 0;
#pragma unroll
      for (int i = 0; i < 4; ++i) {
        float w = w0[i], g = g20[i];
        s1 += w; s3 = fmaf(w, g * g, s3); s4 = fmaf(w, g * e20[i], s4);
        w = w1v[i]; g = g21[i];
        s1 += w; s3 = fmaf(w, g * g, s3); s4 = fmaf(w, g * e21[i], s4);
      }
      s1 = wred(s1); s3 = wred(s3); s4 = wred(s4);
      if (l == 0) {
        V[k * 4 + 0] = s1; V[k * 4 + 1] = s3; V[k * 4 + 2] = s4; V[k * 4 + 3] = 0.f;
      }
    }
  } else {
    // ---- gg + scal
    float a0 = 0, a1 = 0, a2 = 0;
    for (int c = tid; c < DD; c += 256) {
      float g = g2[c], be = be2[c];
      gg[c] = g * g;
      a0 = fmaf(g, g, a0); a1 = fmaf(g, be, a1); a2 = fmaf(be, be, a2);
    }
    a0 = wred(a0); a1 = wred(a1); a2 = wred(a2);
    if (l == 0) { shr[0][wv] = a0; shr[1][wv] = a1; shr[2][wv] = a2; }
    __syncthreads();
    if (tid == 0) {
      scal[0] = shr[0][0] + shr[0][1] + shr[0][2] + shr[0][3];
      scal[1] = shr[1][0] + shr[1][1] + shr[1][2] + shr[1][3];
      scal[2] = shr[2][0] + shr[2][1] + shr[2][2] + shr[2][3];
    }
  }
}

// ---------------- k_pack1: PW1T + PW1B + PCT (136 blocks x 512) ----------------
__global__ __launch_bounds__(512) void k_pack1(
    const float* __restrict__ w1, const float* __restrict__ ln1w,
    const float* __restrict__ cmhg,
    unsigned short* __restrict__ PW1T, unsigned short* __restrict__ PW1B,
    unsigned short* __restrict__ PCT) {
  int b = blockIdx.x;
  if (b < 128) {
    int roff = (b < 64) ? 0 : 512;
    unsigned short* out = (b < 64) ? PW1T : PW1B;
    int tid = (b & 63) * 512 + threadIdx.x;
    int l = tid & 63, t = (tid >> 6) & 15, ct = tid >> 10, g = l >> 4;
    int col = (ct << 4) + (l & 15);
    ushort8 o;
#pragma unroll
    for (int i = 0; i < 8; ++i) {
      int k = t * 32 + g * 8 + i;
      o[i] = f2bf(w1[(size_t)(roff + k) * DD + col] * ln1w[roff + k]);
    }
    *(ushort8*)(out + (size_t)tid * 8) = o;
  } else {
    int tid = (b - 128) * 512 + threadIdx.x; // 4096
    int l = tid & 63, t = (tid >> 6) & 15, g = l >> 4;
    int col = ((tid >> 10) << 4) + (l & 15);
    ushort8 o;
#pragma unroll
    for (int i = 0; i < 8; ++i) {
      int k = t * 32 + g * 8 + i;
      o[i] = f2bf(cmhg[(size_t)col * DD + k]);
    }
    *(ushort8*)(PCT + (size_t)tid * 8) = o;
  }
}

// ---------------- k_gemms: 4 GEMM jobs in one dispatch (304 blocks x 256) ------
__global__ __launch_bounds__(256) void k_gemms(
    const float* __restrict__ q, const float* __restrict__ cm,
    const float* __restrict__ w2,
    const unsigned short* __restrict__ PW1T, const unsigned short* __restrict__ PW1B,
    const unsigned short* __restrict__ PCT,
    float* __restrict__ A, unsigned short* __restrict__ Bwb,
    float* __restrict__ QC, float* __restrict__ M6) {
  int b = blockIdx.x;
  const float* X; const unsigned short* PW; void* Out;
  int bx, by, ostride, obf;
  if (b < 256)      { X = q;  PW = PW1T; Out = A;    bx = b & 7;   by = b >> 3;  ostride = DD;  obf = 0; }
  else if (b < 264) { X = cm; PW = PW1B; Out = Bwb;  bx = b - 256; by = 0;       ostride = DD;  obf = 1; }
  else if (b < 296) { X = q;  PW = PCT;  Out = QC;   bx = 0;       by = b - 264; ostride = NWC; obf = 0; }
  else              { X = w2; PW = PCT;  Out = M6;   bx = 0;       by = b - 296; ostride = NWC; obf = 0; }

  int l = threadIdx.x & 63;
  int wv = threadIdx.x >> 6;
  int lr = l & 15, g = l >> 4;
  int r0 = by * 64 + wv * 16;
  int cb0 = bx * 4;
  f32x4 acc[4] = {{0,0,0,0},{0,0,0,0},{0,0,0,0},{0,0,0,0}};
  const float* xrow = X + (size_t)(r0 + lr) * DD;
#pragma unroll
  for (int t = 0; t < 16; ++t) {
    int kb = t * 32 + g * 8;
    f32x4 x0 = *(const f32x4*)(xrow + kb);
    f32x4 x1 = *(const f32x4*)(xrow + kb + 4);
    union { short8 s; unsigned u[4]; } af;
    af.u[0] = cvtpk2(x0[0], x0[1]);
    af.u[1] = cvtpk2(x0[2], x0[3]);
    af.u[2] = cvtpk2(x1[0], x1[1]);
    af.u[3] = cvtpk2(x1[2], x1[3]);
#pragma unroll
    for (int c = 0; c < 4; ++c) {
      short8 bf = *(const short8*)(PW + (size_t)(((cb0 + c) * 16 + t) * 64 + l) * 8);
      acc[c] = __builtin_amdgcn_mfma_f32_16x16x32_bf16(af.s, bf, acc[c], 0, 0, 0);
    }
  }
#pragma unroll
  for (int c = 0; c < 4; ++c)
#pragma unroll
    for (int r = 0; r < 4; ++r) {
      size_t idx = (size_t)(r0 + g * 4 + r) * ostride + (cb0 + c) * 16 + lr;
      float v = acc[c][r];
      if (obf) ((unsigned short*)Out)[idx] = f2bf(v);
      else     ((float*)Out)[idx] = v;
    }
}

// ---------------- k_pack2: PW2X + PBw + G/C reduce (85 blocks x 512) -----------
__global__ __launch_bounds__(512) void k_pack2(
    const float* __restrict__ w2, const float* __restrict__ M6,
    const float* __restrict__ V, const unsigned short* __restrict__ Bwb,
    const float* __restrict__ Gp, const float* __restrict__ Cp,
    const float* __restrict__ b1,
    unsigned short* __restrict__ PW2X, unsigned short* __restrict__ PBw,
    float* __restrict__ G, float* __restrict__ C) {
  int b = blockIdx.x;
  if (b < 76) {
    int tid = b * 512 + threadIdx.x; // 38912
    int l = tid & 63, t = (tid >> 6) & 15, ct = tid >> 10, g = l >> 4;
    int col = (ct << 4) + (l & 15);
    ushort8 o;
#pragma unroll
    for (int i = 0; i < 8; ++i) {
      int k = t * 32 + g * 8 + i;
      float v;
      if (col < 512)      v = w2[(size_t)k * DD + col];
      else if (col < 576) v = M6[(size_t)k * 64 + (col - 512)];
      else { int cv = col - 576; v = (cv < 3) ? V[k * 4 + cv] : 0.f; }
      o[i] = f2bf(v);
    }
    *(ushort8*)(PW2X + (size_t)tid * 8) = o;
  } else if (b < 84) {
    // PBw[wt][t][l][i] = Bwb[(wt*16 + (l&15))][t*32 + (l>>4)*8 + i]
    int tid = (b - 76) * 512 + threadIdx.x; // 4096
    int l = tid & 63, t = (tid >> 6) & 15, wt = tid >> 10;
    ushort8 o;
#pragma unroll
    for (int i = 0; i < 8; ++i)
      o[i] = Bwb[(size_t)(wt * 16 + (l & 15)) * DD + t * 32 + (l >> 4) * 8 + i];
    *(ushort8*)(PBw + (size_t)tid * 8) = o;
  } else {
    int c = threadIdx.x;
    float g = 0.f, cc = 0.f;
#pragma unroll
    for (int p = 0; p < 16; ++p) { g += Gp[p * DD + c]; cc += Cp[p * DD + c]; }
    G[c] = g; C[c] = cc + b1[c];
  }
}

// ---------------- fused main kernel (256 thr, 2 n's, 2 blocks/CU) --------------

__device__ __forceinline__ void async16(const void* g, void* lds) {
  __builtin_amdgcn_global_load_lds(
      (const __attribute__((address_space(1))) void*)(uintptr_t)g,
      (__attribute__((address_space(3))) void*)(unsigned int)(uintptr_t)lds,
      16, 0, 0);
}

__global__ __launch_bounds__(256, 2) void k_main(
    const float* __restrict__ Afull, const unsigned short* __restrict__ PBw,
    const float* __restrict__ G, const float* __restrict__ Cc,
    const float* __restrict__ q, const float* __restrict__ b2,
    const float* __restrict__ gg, const float* __restrict__ qst,
    const float* __restrict__ QC, const float* __restrict__ c1v,
    const float* __restrict__ c2v, const float* __restrict__ c3v,
    const float* __restrict__ Sq, const float* __restrict__ SSq,
    const float* __restrict__ Sc, const float* __restrict__ SSc,
    const float* __restrict__ scal, const unsigned short* __restrict__ PW2X,
    float* __restrict__ out) {

  __shared__ __align__(16) float sG[DD], sC[DD], sGG[DD];
  __shared__ __align__(16) float sA[2][DD], sQB[2][DD];
  __shared__ __align__(16) unsigned short sW[2][16384];   // 32KB chunk dbuf

  const int tid = threadIdx.x;
  const int wv = tid >> 6, l = tid & 63;
  const int g = l >> 4, lr = l & 15;
  const int n0 = blockIdx.x * 2;
  const int sub = wv >> 1;             // which n of the 2
  const int n = n0 + sub;
  const int whalf = wv & 1;
  const int w0 = whalf * 32 + lr;
  const int w1p = w0 + 16;

  // ---- stage block-wide LDS state ----
  sG[tid] = G[tid]; sG[tid + 256] = G[tid + 256];
  sC[tid] = Cc[tid]; sC[tid + 256] = Cc[tid + 256];
  sGG[tid] = gg[tid]; sGG[tid + 256] = gg[tid + 256];
#pragma unroll
  for (int s = 0; s < 2; ++s) {
    sA[s][tid]       = Afull[(size_t)(n0 + s) * DD + tid];
    sA[s][tid + 256] = Afull[(size_t)(n0 + s) * DD + tid + 256];
    sQB[s][tid]       = q[(size_t)(n0 + s) * DD + tid] + b2[tid];
    sQB[s][tid + 256] = q[(size_t)(n0 + s) * DD + tid + 256] + b2[tid + 256];
  }
  // issue w2x chunk-0 prefetch (overlaps gelu generation)
#pragma unroll
  for (int j = 0; j < 8; ++j)
    async16(PW2X + (size_t)(j * 256 + tid) * 8, &sW[0][(j * 256 + wv * 64) * 8]);

  __syncthreads();

  // ---- LN1 scalars ----
  float sqn = Sq[n], ssqn = SSq[n];
  float mu0 = (sqn + Sc[w0]) * (1.0f / 1024.0f);
  float rs0 = rsqrtf((ssqn + SSc[w0]) * (1.0f / 1024.0f) - mu0 * mu0 + 1e-5f);
  float mu1 = (sqn + Sc[w1p]) * (1.0f / 1024.0f);
  float rs1 = rsqrtf((ssqn + SSc[w1p]) * (1.0f / 1024.0f) - mu1 * mu1 + 1e-5f);
  float al0 = rs0, bl0 = -rs0 * mu0;
  float al1 = rs1, bl1 = -rs1 * mu1;

  // ---- gelu fragments straight into MFMA B-operand layout ----
  short8 af0[16], af1[16];
  const unsigned short* pb0 = PBw + (size_t)(whalf * 2) * 16 * 512;     // wtile base
  const unsigned short* pb1 = PBw + (size_t)(whalf * 2 + 1) * 16 * 512;
#pragma unroll
  for (int t = 0; t < 16; ++t) {
    int kb = t * 32 + g * 8;
    f32x4 a0 = *(const f32x4*)&sA[sub][kb];
    f32x4 a1 = *(const f32x4*)&sA[sub][kb + 4];
    f32x4 g0 = *(const f32x4*)&sG[kb];
    f32x4 g1v = *(const f32x4*)&sG[kb + 4];
    f32x4 c0 = *(const f32x4*)&sC[kb];
    f32x4 c1f = *(const f32x4*)&sC[kb + 4];
    ushort8 ub0 = *(const ushort8*)(pb0 + (size_t)(t * 64 + l) * 8);
    ushort8 ub1 = *(const ushort8*)(pb1 + (size_t)(t * 64 + l) * 8);
    float hA[8], hB[8];
#pragma unroll
    for (int i = 0; i < 4; ++i) {
      float in0 = fmaf(bl0, g0[i], c0[i]);
      float in1 = fmaf(bl1, g0[i], c0[i]);
      hA[i] = gelu_f(fmaf(al0, a0[i] + bf2f(ub0[i]), in0));
      hB[i] = gelu_f(fmaf(al1, a0[i] + bf2f(ub1[i]), in1));
      float jn0 = fmaf(bl0, g1v[i], c1f[i]);
      float jn1 = fmaf(bl1, g1v[i], c1f[i]);
      hA[4 + i] = gelu_f(fmaf(al0, a1[i] + bf2f(ub0[4 + i]), jn0));
      hB[4 + i] = gelu_f(fmaf(al1, a1[i] + bf2f(ub1[4 + i]), jn1));
    }
    union { short8 s; unsigned u[4]; } pa, pb;
    pa.u[0] = cvtpk2(hA[0], hA[1]); pa.u[1] = cvtpk2(hA[2], hA[3]);
    pa.u[2] = cvtpk2(hA[4], hA[5]); pa.u[3] = cvtpk2(hA[6], hA[7]);
    pb.u[0] = cvtpk2(hB[0], hB[1]); pb.u[1] = cvtpk2(hB[2], hB[3]);
    pb.u[2] = cvtpk2(hB[4], hB[5]); pb.u[3] = cvtpk2(hB[6], hB[7]);
    af0[t] = pa.s; af1[t] = pb.s;
  }

  float S20 = 0.f, S50 = 0.f, S21 = 0.f, S51 = 0.f;
  float m6d0 = 0.f, m6d1 = 0.f;
  float v1d0 = 0.f, v3d0 = 0.f, v4d0 = 0.f;
  float v1d1 = 0.f, v3d1 = 0.f, v4d1 = 0.f;

  for (int cc = 0; cc < NCHUNK; ++cc) {
    __syncthreads();                    // chunk cc staged; prev chunk reads done
    if (cc < NCHUNK - 1) {
      const unsigned short* src = PW2X + (size_t)(cc + 1) * 16384;
      unsigned short* dst = sW[(cc + 1) & 1];
#pragma unroll
      for (int j = 0; j < 8; ++j)
        async16(src + (size_t)(j * 256 + tid) * 8, &dst[(j * 256 + wv * 64) * 8]);
    }
    const unsigned short* wbuf = sW[cc & 1];

    if (cc < 16) {
      f32x4 acc00 = {0,0,0,0}, acc01 = {0,0,0,0}, acc10 = {0,0,0,0}, acc11 = {0,0,0,0};
#pragma unroll
      for (int t = 0; t < 16; ++t) {
        short8 bf0 = *(const short8*)(wbuf + (size_t)((t * 64 + l) * 8));
        short8 bf1 = *(const short8*)(wbuf + (size_t)(((16 + t) * 64 + l) * 8));
        acc00 = __builtin_amdgcn_mfma_f32_16x16x32_bf16(bf0, af0[t], acc00, 0, 0, 0);
        acc10 = __builtin_amdgcn_mfma_f32_16x16x32_bf16(bf0, af1[t], acc10, 0, 0, 0);
        acc01 = __builtin_amdgcn_mfma_f32_16x16x32_bf16(bf1, af0[t], acc01, 0, 0, 0);
        acc11 = __builtin_amdgcn_mfma_f32_16x16x32_bf16(bf1, af1[t], acc11, 0, 0, 0);
      }
#pragma unroll
      for (int ct = 0; ct < 2; ++ct) {
        int cb = cc * 32 + ct * 16 + g * 4;
        f32x4 qb4 = *(const f32x4*)&sQB[sub][cb];
        f32x4 gg4 = *(const f32x4*)&sGG[cb];
        f32x4 aAv = ct ? acc01 : acc00;
        f32x4 aBv = ct ? acc11 : acc10;
#pragma unroll
        for (int r = 0; r < 4; ++r) {
          float y = aAv[r] + qb4[r];
          float y2 = y * y;
          S20 += y2; S50 = fmaf(y2, gg4[r], S50);
          float z = aBv[r] + qb4[r];
          float z2 = z * z;
          S21 += z2; S51 = fmaf(z2, gg4[r], S51);
        }
      }
    } else if (cc == 16 + whalf) {
      f32x4 acc00 = {0,0,0,0}, acc11 = {0,0,0,0};
#pragma unroll
      for (int t = 0; t < 16; ++t) {
        short8 bf0 = *(const short8*)(wbuf + (size_t)((t * 64 + l) * 8));
        short8 bf1 = *(const short8*)(wbuf + (size_t)(((16 + t) * 64 + l) * 8));
        acc00 = __builtin_amdgcn_mfma_f32_16x16x32_bf16(bf0, af0[t], acc00, 0, 0, 0);
        acc11 = __builtin_amdgcn_mfma_f32_16x16x32_bf16(bf1, af1[t], acc11, 0, 0, 0);
      }
      float d0 = sel4(acc00, lr & 3);
      float d1 = sel4(acc11, lr & 3);
      int src = lr + ((lr >> 2) << 4);
      m6d0 = __shfl(d0, src, 64);
      m6d1 = __shfl(d1, src, 64);
    } else if (cc == 18) {
      f32x4 acc00 = {0,0,0,0}, acc10 = {0,0,0,0};
#pragma unroll
      for (int t = 0; t < 16; ++t) {
        short8 bf0 = *(const short8*)(wbuf + (size_t)((t * 64 + l) * 8));
        acc00 = __builtin_amdgcn_mfma_f32_16x16x32_bf16(bf0, af0[t], acc00, 0, 0, 0);
        acc10 = __builtin_amdgcn_mfma_f32_16x16x32_bf16(bf0, af1[t], acc10, 0, 0, 0);
      }
      v1d0 = __shfl(acc00[0], lr, 64);
      v3d0 = __shfl(acc00[1], lr, 64);
      v4d0 = __shfl(acc00[2], lr, 64);
      v1d1 = __shfl(acc10[0], lr, 64);
      v3d1 = __shfl(acc10[1], lr, 64);
      v4d1 = __shfl(acc10[2], lr, 64);
    }
  }

  S20 += __shfl_xor(S20, 16, 64); S20 += __shfl_xor(S20, 32, 64);
  S50 += __shfl_xor(S50, 16, 64); S50 += __shfl_xor(S50, 32, 64);
  S21 += __shfl_xor(S21, 16, 64); S21 += __shfl_xor(S21, 32, 64);
  S51 += __shfl_xor(S51, 16, 64); S51 += __shfl_xor(S51, 32, 64);

  if (g == 0) {
    float sg2v = scal[0], sgbv = scal[1], sb2v = scal[2];
    float qbs = qst[n * 4 + 0], qggs = qst[n * 4 + 1], qgbs = qst[n * 4 + 2];
#pragma unroll
    for (int p = 0; p < 2; ++p) {
      int w = whalf * 32 + p * 16 + lr;
      float S1 = (p ? v1d1 : v1d0) + qbs;
      float S2 = (p ? S21 : S20);
      float S3 = (p ? v3d1 : v3d0) + qggs;
      float S4 = (p ? v4d1 : v4d0) + qgbs;
      float S5 = (p ? S51 : S50);
      float S6 = (p ? m6d1 : m6d0) + QC[(size_t)n * NWC + w] + c3v[w];
      float mu2 = S1 * (1.0f / 512.0f);
      float var2 = S2 * (1.0f / 512.0f) - mu2 * mu2;
      float rs2 = rsqrtf(var2 + 1e-5f);
      float n2 = rs2 * rs2 * (S5 - 2.f * mu2 * S3 + mu2 * mu2 * sg2v)
               + 2.f * rs2 * (S4 - mu2 * sgbv) + sb2v;
      float num = rs2 * (S6 - mu2 * c1v[w]) + c2v[w];
      out[(size_t)n * NWC + w] = 16.0f * num / fmaxf(sqrtf(fmaxf(n2, 0.f)), 1e-12f);
    }
  }
}

// ---------------- launch ----------------

extern "C" void kernel_launch(void* const* d_in, const int* in_sizes, int n_in,
                              void* d_out, int out_size, void* d_ws, size_t ws_size,
                              hipStream_t stream) {
  const float* q    = (const float*)d_in[0];
  const float* cm   = (const float*)d_in[1];
  const float* ln1w = (const float*)d_in[2];
  const float* ln1b = (const float*)d_in[3];
  const float* w1   = (const float*)d_in[4];
  const float* b1   = (const float*)d_in[5];
  const float* w2   = (const float*)d_in[6];
  const float* b2   = (const float*)d_in[7];
  const float* ln2w = (const float*)d_in[8];
  const float* ln2b = (const float*)d_in[9];
  float* out = (float*)d_out;

  char* p = (char*)d_ws;
  auto alloc = [&](size_t bytes) { char* r = p; p += (bytes + 255) & ~(size_t)255; return r; };
  float* A     = (float*)alloc((size_t)NQ * DD * 4);
  unsigned short* Bwb = (unsigned short*)alloc((size_t)NWC * DD * 2);
  float* G     = (float*)alloc(DD * 4);
  float* C     = (float*)alloc(DD * 4);
  float* Gp    = (float*)alloc((size_t)16 * DD * 4);
  float* Cp    = (float*)alloc((size_t)16 * DD * 4);
  float* Sq    = (float*)alloc(NQ * 4);
  float* SSq   = (float*)alloc(NQ * 4);
  float* Sc    = (float*)alloc(NWC * 4);
  float* SSc   = (float*)alloc(NWC * 4);
  float* cmhg  = (float*)alloc((size_t)NWC * DD * 4);
  float* c1    = (float*)alloc(NWC * 4);
  float* c2    = (float*)alloc(NWC * 4);
  float* c3    = (float*)alloc(NWC * 4);
  float* gg    = (float*)alloc(DD * 4);
  float* scal  = (float*)alloc(256);
  float* qst   = (float*)alloc((size_t)NQ * 4 * 4);
  float* QC    = (float*)alloc((size_t)NQ * NWC * 4);
  float* M6buf = (float*)alloc((size_t)DD * NWC * 4);
  float* Vbuf  = (float*)alloc((size_t)DD * 4 * 4);
  unsigned short* PW1T = (unsigned short*)alloc((size_t)DD * DD * 2);
  unsigned short* PW1B = (unsigned short*)alloc((size_t)DD * DD * 2);
  unsigned short* PCT  = (unsigned short*)alloc((size_t)DD * NWC * 2);
  unsigned short* PBw  = (unsigned short*)alloc((size_t)NWC * DD * 2);
  unsigned short* PW2X = (unsigned short*)alloc((size_t)NCHUNK * 16384 * 2);

  k_prep<<<401, 256, 0, stream>>>(q, cm, ln1w, ln1b, w1, w2, ln2w, ln2b, b2,
                                  Sq, SSq, qst, Sc, SSc, cmhg, c1, c2, c3,
                                  Gp, Cp, Vbuf, gg, scal);
  k_pack1<<<136, 512, 0, stream>>>(w1, ln1w, cmhg, PW1T, PW1B, PCT);
  k_gemms<<<304, 256, 0, stream>>>(q, cm, w2, PW1T, PW1B, PCT, A, Bwb, QC, M6buf);
  k_pack2<<<85, 512, 0, stream>>>(w2, M6buf, Vbuf, Bwb, Gp, Cp, b1, PW2X, PBw, G, C);
  k_main<<<1024, 256, 0, stream>>>(A, PBw, G, C, q, b2, gg, qst, QC, c1, c2, c3,
                                   Sq, SSq, Sc, SSc, scal, PW2X, out);
}